// Round 3
// baseline (21425.345 us; speedup 1.0000x reference)
//
#include <hip/hip_runtime.h>
#include <hip/hip_bf16.h>
#include <hip/hip_fp16.h>

// ============================================================================
// 2-layer LSTM (TF BasicLSTMCell, forget_bias=1), B=32, T=2048, D=H=256.
// R3: fused persistent recurrence. 256 WGs (L,b,s) x 256 thr (gate g, col j).
// All 512 weights per thread live in 256 VGPRs (loaded once). Cross-WG h
// exchange via f16 trace in ws + agent-scope flag counters (4 producers/flag).
// Layer 2 pipelines ~1 step behind layer 1. No GEMM, no per-step L2 weight
// streaming (R2's wall: 512KB/step/CU from L2 = 4.2us/step).
// ============================================================================

typedef _Float16 half_t;
typedef __attribute__((ext_vector_type(2))) _Float16 h2v;
union U4 { uint4 u; h2v h[4]; };

static __device__ __forceinline__ float bf2f(unsigned short u) {
  union { unsigned u; float f; } v; v.u = ((unsigned)u) << 16; return v.f;
}
static __device__ __forceinline__ unsigned short f2bf(float f) {
  union { float f; unsigned u; } v; v.f = f;
  unsigned r = v.u + 0x7fffu + ((v.u >> 16) & 1u);
  return (unsigned short)(r >> 16);
}
static __device__ __forceinline__ float ldw(const void* p, long i, int fp32) {
  return fp32 ? ((const float*)p)[i] : bf2f(((const unsigned short*)p)[i]);
}
static __device__ __forceinline__ float rcpf(float x) { return __builtin_amdgcn_rcpf(x); }
static __device__ __forceinline__ float sigm(float x) { return rcpf(1.f + __expf(-x)); }
static __device__ __forceinline__ float tanh_(float x) {
  float e = __expf(-2.f * fabsf(x));
  float t = (1.f - e) * rcpf(1.f + e);
  return copysignf(t, x);
}
static __device__ __forceinline__ float fdot2(h2v a, h2v b, float c) {
#if __has_builtin(__builtin_amdgcn_fdot2)
  return __builtin_amdgcn_fdot2(a, b, c, false);
#else
  return c + (float)a.x * (float)b.x + (float)a.y * (float)b.y;
#endif
}

// ----------------------------------------------------------------------------
// detect: bf16 N(0,1) never has exponent bits >= 192; fp32 low halves are
// ~uniform (~25% hit). flag=1 -> fp32 inputs.
// ----------------------------------------------------------------------------
__global__ __launch_bounds__(256) void detect(const unsigned short* __restrict__ x,
                                              int* __restrict__ flag) {
  __shared__ int cnt;
  if (threadIdx.x == 0) cnt = 0;
  __syncthreads();
  int c = 0;
#pragma unroll
  for (int i = 0; i < 8; ++i) {
    unsigned short u = x[threadIdx.x * 8 + i];
    c += (((u >> 7) & 0xFF) >= 192) ? 1 : 0;
  }
  atomicAdd(&cnt, c);
  __syncthreads();
  if (threadIdx.x == 0) *flag = (cnt > 16) ? 1 : 0;
}

// ----------------------------------------------------------------------------
// prep:
//  y=0: Wpk pack, id in [0,2^20): e=id&7, tid=(id>>3)&255, c=(id>>11)&63,
//       s=(id>>17)&3, L=id>>19; row=c*8+e, col=(tid>>6)*256+s*64+(tid&63);
//       Wpk[id] = f16(W_L[row*1024+col]).  (c<32: x/h1-part rows; c>=32: h-part)
//  y=1: biases (fp32), zero H1[0]/H2[0], zero flags (+seed t=0 flags to 4).
// ----------------------------------------------------------------------------
__global__ __launch_bounds__(256) void prep(
    const void* __restrict__ W0, const void* __restrict__ W1,
    const void* __restrict__ b0, const void* __restrict__ b1,
    const int* __restrict__ flag,
    half_t* __restrict__ Wpk, float* __restrict__ bias0, float* __restrict__ bias1,
    half_t* __restrict__ H1, half_t* __restrict__ H2,
    int* __restrict__ flag1, int* __restrict__ flag2)
{
  const int fp32 = *flag;
  int id = blockIdx.x * 256 + threadIdx.x;
  if (blockIdx.y == 0) {
    int e = id & 7, tid = (id >> 3) & 255, c = (id >> 11) & 63,
        s = (id >> 17) & 3, L = (id >> 19) & 1;
    int row = c * 8 + e;
    int col = (tid >> 6) * 256 + s * 64 + (tid & 63);
    Wpk[id] = (half_t)ldw(L ? W1 : W0, (long)row * 1024 + col, fp32);
  } else {
    if (id < 1024)            bias0[id] = ldw(b0, id, fp32);
    else if (id < 2048)       bias1[id - 1024] = ldw(b1, id - 1024, fp32);
    else if (id < 10240)      H1[id - 2048] = (half_t)0.f;
    else if (id < 18432)      H2[id - 10240] = (half_t)0.f;
    else if (id < 83\
968 + 32) { // 18432 + 65568 = 84000; written explicitly below
      int i = id - 18432;
      if (i < 65568) flag1[i] = (i < 32) ? 4 : 0;
    }
    if (id >= 84000 && id < 149568) {
      int i = id - 84000;
      flag2[i] = (i < 32) ? 4 : 0;
    }
  }
}

// ----------------------------------------------------------------------------
// conv_x: full x -> f16 (exact for bf16 input; 5e-4 rel for fp32)
// ----------------------------------------------------------------------------
__global__ __launch_bounds__(256) void conv_x(const void* __restrict__ x,
                                              const int* __restrict__ flag,
                                              half_t* __restrict__ xf) {
  const int fp32 = *flag;
  long gid = (long)blockIdx.x * 256 + threadIdx.x;
  xf[gid] = (half_t)ldw(x, gid, fp32);
}

// ----------------------------------------------------------------------------
// recur: persistent fused 2-layer recurrence.
// blockIdx = L*128 + q*32 + s*8 + r ; b = q*8+r  (layer1 dispatched first;
// same-b WGs share an XCD residue). 1 WG/CU (VGPR>256 by construction).
// ----------------------------------------------------------------------------
__global__ __launch_bounds__(256, 1) void recur(
    const half_t* __restrict__ xf, const uint4* __restrict__ Wpk,
    const float* __restrict__ bias0, const float* __restrict__ bias1,
    half_t* H1, half_t* H2, int* flag1, int* flag2,
    void* __restrict__ dout, const int* __restrict__ dtf)
{
  const int fp32 = *dtf;
  const int bi = blockIdx.x;
  const int L = bi >> 7, r = bi & 7, s = (bi >> 3) & 3, q = (bi >> 5) & 3;
  const int b = q * 8 + r;
  const int tid = threadIdx.x;
  const int g = tid >> 6, j = tid & 63;

  __shared__ float gl[4][64];

  // weights: 64 x uint4 = 256 VGPRs, loaded once, never reloaded
  U4 w[64];
  const uint4* wp = Wpk + (size_t)((L * 4 + s) * 64) * 256;
#pragma unroll
  for (int c = 0; c < 64; ++c) w[c].u = wp[c * 256 + tid];

  const float bs = (L ? bias1 : bias0)[g * 256 + s * 64 + j];
  float cst = 0.f;

  half_t* Hown = L ? H2 : H1;
  int* fOwn = L ? flag2 : flag1;

  for (int t = 0; t < 2048; ++t) {
    if (tid == 0) {
      while (__hip_atomic_load(&fOwn[t * 32 + b], __ATOMIC_ACQUIRE,
                               __HIP_MEMORY_SCOPE_AGENT) < 4)
        __builtin_amdgcn_s_sleep(2);
      if (L)
        while (__hip_atomic_load(&flag1[(t + 1) * 32 + b], __ATOMIC_ACQUIRE,
                                 __HIP_MEMORY_SCOPE_AGENT) < 4)
          __builtin_amdgcn_s_sleep(2);
    }
    __syncthreads();

    // A-part input: layer1 = xf[b][t][:], layer2 = H1[t+1][b][:]
    const U4* A = (const U4*)(L ? (const half_t*)(H1 + (size_t)(t + 1) * 8192 + b * 256)
                                : (xf + ((size_t)b * 2048 + t) * 256));
    const U4* Bp = (const U4*)(Hown + (size_t)t * 8192 + b * 256);

    float ac[4] = {0.f, 0.f, 0.f, 0.f};
#pragma unroll
    for (int c = 0; c < 32; ++c) {
      U4 av; av.u = A[c].u;
      float a = ac[c & 3];
      a = fdot2(av.h[0], w[c].h[0], a);
      a = fdot2(av.h[1], w[c].h[1], a);
      a = fdot2(av.h[2], w[c].h[2], a);
      a = fdot2(av.h[3], w[c].h[3], a);
      ac[c & 3] = a;
    }
#pragma unroll
    for (int c = 0; c < 32; ++c) {
      U4 bv; bv.u = Bp[c].u;
      float a = ac[c & 3];
      a = fdot2(bv.h[0], w[32 + c].h[0], a);
      a = fdot2(bv.h[1], w[32 + c].h[1], a);
      a = fdot2(bv.h[2], w[32 + c].h[2], a);
      a = fdot2(bv.h[3], w[32 + c].h[3], a);
      ac[c & 3] = a;
    }
    gl[g][j] = (ac[0] + ac[1]) + (ac[2] + ac[3]) + bs;
    __syncthreads();   // gates ready; also protects gl reuse via loop-top barrier

    if (g == 0) {      // wave 0: elementwise + publish
      float gi = gl[0][j], gj = gl[1][j], gf = gl[2][j], go = gl[3][j];
      float cn = cst * sigm(gf + 1.f) + sigm(gi) * tanh_(gj);
      cst = cn;
      float h = tanh_(cn) * sigm(go);
      half_t* Hc = L ? H2 : H1;
      Hc[(size_t)(t + 1) * 8192 + b * 256 + s * 64 + j] = (half_t)h;
      if (L) {
        size_t oi = ((size_t)b * 2048 + t) * 256 + s * 64 + j;
        if (fp32) ((float*)dout)[oi] = h;
        else      ((unsigned short*)dout)[oi] = f2bf(h);
      }
      __threadfence();                       // agent-scope release of h stores
      if (j == 0)
        __hip_atomic_fetch_add(&fOwn[(t + 1) * 32 + b], 1, __ATOMIC_RELEASE,
                               __HIP_MEMORY_SCOPE_AGENT);
    }
  }
}

// ----------------------------------------------------------------------------
extern "C" void kernel_launch(void* const* d_in, const int* in_sizes, int n_in,
                              void* d_out, int out_size, void* d_ws, size_t ws_size,
                              hipStream_t stream) {
  const void* x  = d_in[0];   // [32][2048][256]
  const void* W0 = d_in[1];   // [512][1024]
  const void* b0 = d_in[2];   // [1024]
  const void* W1 = d_in[3];   // [512][1024]
  const void* b1 = d_in[4];   // [1024]

  // ws layout (~103.3 MB; proven ws >= ~203 MB in R2)
  char* p = (char*)d_ws;
  half_t* xf   = (half_t*)p;  p += (size_t)16777216 * 2;   // 33.55 MB
  half_t* Wpk  = (half_t*)p;  p += (size_t)1048576 * 2;    // 2 MB
  float* bias0 = (float*)p;   p += 4096;
  float* bias1 = (float*)p;   p += 4096;
  half_t* H1   = (half_t*)p;  p += (size_t)2049 * 8192 * 2; // 33.57 MB
  half_t* H2   = (half_t*)p;  p += (size_t)2049 * 8192 * 2; // 33.57 MB
  int* flag1   = (int*)p;     p += 65568 * 4;
  int* flag2   = (int*)p;     p += 65568 * 4;
  int* dflag   = (int*)p;     p += 256;

  detect<<<1, 256, 0, stream>>>((const unsigned short*)x, dflag);
  conv_x<<<65536, 256, 0, stream>>>(x, dflag, xf);
  prep<<<dim3(4096, 2), 256, 0, stream>>>(W0, W1, b0, b1, dflag,
                                          Wpk, bias0, bias1, H1, H2,
                                          flag1, flag2);
  recur<<<256, 256, 0, stream>>>(xf, (const uint4*)Wpk, bias0, bias1,
                                 H1, H2, flag1, flag2, d_out, dflag);
}

// Round 4
// 10010.703 us; speedup vs baseline: 2.1402x; 2.1402x over previous
//
#include <hip/hip_runtime.h>
#include <hip/hip_bf16.h>
#include <hip/hip_fp16.h>

// ============================================================================
// 2-layer LSTM (TF BasicLSTMCell, forget_bias=1), B=32, T=2048, D=H=256.
// R4: G1 = x@W0x + b0 precomputed by MFMA GEMM (f16). Persistent recurrence:
// 256 WGs = 2 layers x 32 batches x 4 column-slices, 512 threads
// (thread = column c in slice x K-half kq). Weights register-resident:
// L2 = 32 uint4 (128 VGPR), L1 = 16 uint4 (64 VGPR)  -> no spill (R3 bug).
// Cross-WG handoff: normal b128 h stores + release flag store; consumers
// relaxed-poll flags + one acquire load (buffer_inv), then normal loads.
// H1 = full trace (L2 lags L1); H2 = depth-4 ring (sibling skew <= 1).
// ============================================================================

typedef __attribute__((ext_vector_type(8))) _Float16 f16x8;
typedef __attribute__((ext_vector_type(8))) unsigned short ushort8;
typedef __attribute__((ext_vector_type(4))) float f32x4;
typedef _Float16 half_t;
typedef __attribute__((ext_vector_type(2))) _Float16 h2v;
union U4 { uint4 u; h2v h[4]; };

static __device__ __forceinline__ float bf2f(unsigned short u) {
  union { unsigned u; float f; } v; v.u = ((unsigned)u) << 16; return v.f;
}
static __device__ __forceinline__ unsigned short f2bf(float f) {
  union { float f; unsigned u; } v; v.f = f;
  unsigned r = v.u + 0x7fffu + ((v.u >> 16) & 1u);
  return (unsigned short)(r >> 16);
}
static __device__ __forceinline__ float ldw(const void* p, long i, int fp32) {
  return fp32 ? ((const float*)p)[i] : bf2f(((const unsigned short*)p)[i]);
}
static __device__ __forceinline__ float rcpf(float x) { return __builtin_amdgcn_rcpf(x); }
static __device__ __forceinline__ float sigm(float x) { return rcpf(1.f + __expf(-x)); }
static __device__ __forceinline__ float tanh_(float x) {
  float e = __expf(-2.f * fabsf(x));
  float t = (1.f - e) * rcpf(1.f + e);
  return copysignf(t, x);
}
static __device__ __forceinline__ float fdot2(h2v a, h2v b, float c) {
#if __has_builtin(__builtin_amdgcn_fdot2)
  return __builtin_amdgcn_fdot2(a, b, c, false);
#else
  return c + (float)a.x * (float)b.x + (float)a.y * (float)b.y;
#endif
}

// ---------------------------------------------------------------- detect ----
__global__ __launch_bounds__(256) void detect(const unsigned short* __restrict__ x,
                                              int* __restrict__ flag) {
  __shared__ int cnt;
  if (threadIdx.x == 0) cnt = 0;
  __syncthreads();
  int c = 0;
#pragma unroll
  for (int i = 0; i < 8; ++i) {
    unsigned short u = x[threadIdx.x * 8 + i];
    c += (((u >> 7) & 0xFF) >= 192) ? 1 : 0;
  }
  atomicAdd(&cnt, c);
  __syncthreads();
  if (threadIdx.x == 0) *flag = (cnt > 16) ? 1 : 0;
}

// ------------------------------------------------------------------ prep ----
// task0: Wrec pack (786432 f16). uint4 idx: L1 (uid<32768): (s*16+ch)*512+tid,
//   row=256+(tid>>8)*128+ch*8+e from W0. L2: 32768+(s*32+ch)*512+tid,
//   row=(tid>>8)*256+ch*8+e from W1. col=((tid>>6)&3)*256+s*64+(tid&63).
// task1: BT0[n*256+k] = f16(W0[k*1024+n])   (x-part transposed, k<256)
// task2: bias0/bias1 fp32; zero H1[0] (8192 f16) and H2 ring (32768 f16)
// task3/4: flag1/flag2 = 1 for t=0 (first 128 ints) else 0   (2049*128 ints)
// ----------------------------------------------------------------------------
__global__ __launch_bounds__(256) void prep(
    const void* __restrict__ W0, const void* __restrict__ W1,
    const void* __restrict__ b0, const void* __restrict__ b1,
    const int* __restrict__ dtf,
    half_t* __restrict__ Wrec, half_t* __restrict__ BT0,
    float* __restrict__ bias0, float* __restrict__ bias1,
    half_t* __restrict__ H1, half_t* __restrict__ H2r,
    int* __restrict__ flag1, int* __restrict__ flag2)
{
  const int fp32 = *dtf;
  int id = blockIdx.x * 256 + threadIdx.x;
  int task = blockIdx.y;
  if (task == 0) {
    int uid = id >> 3, e = id & 7;
    int row, col;
    const void* W;
    if (uid < 32768) {
      int tid = uid & 511, sc = uid >> 9;       // sc = s*16+ch
      int ch = sc & 15, s = sc >> 4;
      row = 256 + (tid >> 8) * 128 + ch * 8 + e;
      col = ((tid >> 6) & 3) * 256 + s * 64 + (tid & 63);
      W = W0;
    } else {
      int u = uid - 32768;
      int tid = u & 511, sc = u >> 9;           // sc = s*32+ch
      int ch = sc & 31, s = sc >> 5;
      row = (tid >> 8) * 256 + ch * 8 + e;
      col = ((tid >> 6) & 3) * 256 + s * 64 + (tid & 63);
      W = W1;
    }
    Wrec[id] = (half_t)ldw(W, (long)row * 1024 + col, fp32);
  } else if (task == 1) {
    if (id < 262144) {
      int n = id >> 8, k = id & 255;
      BT0[id] = (half_t)ldw(W0, (long)k * 1024 + n, fp32);
    }
  } else if (task == 2) {
    if (id < 1024)       bias0[id] = ldw(b0, id, fp32);
    else if (id < 2048)  bias1[id - 1024] = ldw(b1, id - 1024, fp32);
    else if (id < 10240) H1[id - 2048] = (half_t)0.f;
    else if (id < 43008) H2r[id - 10240] = (half_t)0.f;
  } else if (task == 3) {
    if (id < 262272) flag1[id] = (id < 128) ? 1 : 0;
  } else {
    if (id < 262272) flag2[id] = (id < 128) ? 1 : 0;
  }
}

// --------------------------------------------------------------- gemm_xw ----
// G1[row][1024](f16) = x[row][256] @ BT0^T + bias0, row = b*2048+t (65536).
// 128x128 tile, 4 waves 2x2, K=256 in registers, dtype branch on A loads.
// ----------------------------------------------------------------------------
__global__ __launch_bounds__(256) void gemm_xw(
    const void* __restrict__ A, const half_t* __restrict__ BT,
    const float* __restrict__ bias, half_t* __restrict__ G,
    const int* __restrict__ dtf)
{
  const int fp32 = *dtf;
  const int lane = threadIdx.x & 63;
  const int wave = threadIdx.x >> 6;
  const int wm = wave >> 1, wn = wave & 1;
  const int m0 = blockIdx.x * 128 + wm * 64;
  const int n0 = blockIdx.y * 128 + wn * 64;
  const int lm = lane & 15;
  const int q  = lane >> 4;

  f32x4 acc[4][4] = {};
  long aoff[4], boff[4];
#pragma unroll
  for (int fm = 0; fm < 4; ++fm)
    aoff[fm] = (long)(m0 + fm * 16 + lm) * 256 + q * 8;
#pragma unroll
  for (int fn = 0; fn < 4; ++fn)
    boff[fn] = (long)(n0 + fn * 16 + lm) * 256 + q * 8;

#pragma unroll
  for (int kt = 0; kt < 8; ++kt) {
    f16x8 aF[4], bF[4];
    if (fp32) {
#pragma unroll
      for (int fm = 0; fm < 4; ++fm) {
        const float* ap = (const float*)A + aoff[fm] + kt * 32;
        float4 f0 = *(const float4*)ap, f1 = *(const float4*)(ap + 4);
        aF[fm][0] = (half_t)f0.x; aF[fm][1] = (half_t)f0.y;
        aF[fm][2] = (half_t)f0.z; aF[fm][3] = (half_t)f0.w;
        aF[fm][4] = (half_t)f1.x; aF[fm][5] = (half_t)f1.y;
        aF[fm][6] = (half_t)f1.z; aF[fm][7] = (half_t)f1.w;
      }
    } else {
#pragma unroll
      for (int fm = 0; fm < 4; ++fm) {
        ushort8 u = *(const ushort8*)((const unsigned short*)A + aoff[fm] + kt * 32);
#pragma unroll
        for (int e = 0; e < 8; ++e) aF[fm][e] = (half_t)bf2f(u[e]);
      }
    }
#pragma unroll
    for (int fn = 0; fn < 4; ++fn)
      bF[fn] = *(const f16x8*)(BT + boff[fn] + kt * 32);
#pragma unroll
    for (int fm = 0; fm < 4; ++fm)
#pragma unroll
      for (int fn = 0; fn < 4; ++fn)
        acc[fm][fn] = __builtin_amdgcn_mfma_f32_16x16x32_f16(
            aF[fm], bF[fn], acc[fm][fn], 0, 0, 0);
  }
#pragma unroll
  for (int fm = 0; fm < 4; ++fm)
#pragma unroll
    for (int fn = 0; fn < 4; ++fn) {
      int col = n0 + fn * 16 + lm;
      float bs = bias[col];
#pragma unroll
      for (int r = 0; r < 4; ++r) {
        int row = m0 + fm * 16 + q * 4 + r;
        G[(size_t)row * 1024 + col] = (half_t)(acc[fm][fn][r] + bs);
      }
    }
}

// ----------------------------------------------------------------- recur ----
__global__ __launch_bounds__(512, 1) void recur(
    const half_t* __restrict__ G1, const uint4* __restrict__ Wrec,
    const float* __restrict__ bias1,
    half_t* H1, half_t* H2r, int* flag1, int* flag2,
    void* __restrict__ dout, const int* __restrict__ dtf)
{
  const int fp32 = *dtf;
  const int bi = blockIdx.x;
  const int L = bi >> 7, s = (bi >> 5) & 3, b = bi & 31;
  const int tid = threadIdx.x;
  const int kq = tid >> 8, c = tid & 255;
  const int g = c >> 6, j = c & 63;

  __shared__ __align__(16) half_t hbuf[512];
  __shared__ float part[2][256];
  __shared__ float glf[256];
  __shared__ __align__(16) half_t hlds[64];

  // register-resident weights: L2 uses w[0..31] (128 VGPR), L1 w[0..15]
  U4 w[32];
  const uint4* wp = Wrec + (L ? 32768 + s * 32 * 512 : s * 16 * 512);
#pragma unroll
  for (int ch = 0; ch < 32; ++ch) w[ch].u = wp[ch * 512 + tid];  // L1: upper 16 unused

  const int scol = g * 256 + s * 64 + j;            // full gate-column index
  const float bsv = (L && tid < 256) ? bias1[scol] : 0.f;
  int* fOwn = L ? flag2 : flag1;
  float cst = 0.f;
  const unsigned long long ONE2 = 0x0000000100000001ull;

  for (int t = 0; t < 2048; ++t) {
    // ---- wait for inputs ----
    if (tid == 0) {
      volatile unsigned long long* fo =
          (volatile unsigned long long*)(fOwn + t * 128 + b * 4);
      if (L) {
        volatile unsigned long long* fx =
            (volatile unsigned long long*)(flag1 + (t + 1) * 128 + b * 4);
        for (;;) {
          unsigned long long a0 = __hip_atomic_load((unsigned long long*)&fo[0],
              __ATOMIC_RELAXED, __HIP_MEMORY_SCOPE_AGENT);
          unsigned long long a1 = __hip_atomic_load((unsigned long long*)&fo[1],
              __ATOMIC_RELAXED, __HIP_MEMORY_SCOPE_AGENT);
          unsigned long long b0 = __hip_atomic_load((unsigned long long*)&fx[0],
              __ATOMIC_RELAXED, __HIP_MEMORY_SCOPE_AGENT);
          unsigned long long b1 = __hip_atomic_load((unsigned long long*)&fx[1],
              __ATOMIC_RELAXED, __HIP_MEMORY_SCOPE_AGENT);
          if ((a0 & a1 & b0 & b1) == ONE2) break;
          __builtin_amdgcn_s_sleep(1);
        }
      } else {
        for (;;) {
          unsigned long long a0 = __hip_atomic_load((unsigned long long*)&fo[0],
              __ATOMIC_RELAXED, __HIP_MEMORY_SCOPE_AGENT);
          unsigned long long a1 = __hip_atomic_load((unsigned long long*)&fo[1],
              __ATOMIC_RELAXED, __HIP_MEMORY_SCOPE_AGENT);
          if ((a0 & a1) == ONE2) break;
          __builtin_amdgcn_s_sleep(1);
        }
      }
      // acquire fence: buffer_inv so subsequent normal loads see fresh data
      (void)__hip_atomic_load(fOwn + t * 128 + b * 4, __ATOMIC_ACQUIRE,
                              __HIP_MEMORY_SCOPE_AGENT);
    }
    __syncthreads();

    // ---- stage inputs into LDS ----
    float g1v = 0.f;
    if (L) {
      if (tid < 32) {
        uint4 v = *(const uint4*)(H1 + ((size_t)(t + 1) * 32 + b) * 256 + tid * 8);
        *(uint4*)&hbuf[tid * 8] = v;
      } else if (tid < 64) {
        int q2 = tid - 32;
        uint4 v = *(const uint4*)(H2r + ((size_t)(t & 3) * 32 + b) * 256 + q2 * 8);
        *(uint4*)&hbuf[256 + q2 * 8] = v;
      }
    } else {
      if (tid < 32) {
        uint4 v = *(const uint4*)(H1 + ((size_t)t * 32 + b) * 256 + tid * 8);
        *(uint4*)&hbuf[tid * 8] = v;
      }
      if (tid < 256)
        g1v = (float)G1[((size_t)b * 2048 + t) * 1024 + scol];
    }
    __syncthreads();

    // ---- matvec: thread (c, kq) ----
    float ac[4] = {0.f, 0.f, 0.f, 0.f};
    const U4* hb = (const U4*)hbuf + (L ? kq * 32 : kq * 16);
    if (L) {
#pragma unroll
      for (int ch = 0; ch < 32; ++ch) {
        U4 hv; hv.u = ((const uint4*)hb)[ch];
        float a = ac[ch & 3];
        a = fdot2(hv.h[0], w[ch].h[0], a);
        a = fdot2(hv.h[1], w[ch].h[1], a);
        a = fdot2(hv.h[2], w[ch].h[2], a);
        a = fdot2(hv.h[3], w[ch].h[3], a);
        ac[ch & 3] = a;
      }
    } else {
#pragma unroll
      for (int ch = 0; ch < 16; ++ch) {
        U4 hv; hv.u = ((const uint4*)hb)[ch];
        float a = ac[ch & 3];
        a = fdot2(hv.h[0], w[ch].h[0], a);
        a = fdot2(hv.h[1], w[ch].h[1], a);
        a = fdot2(hv.h[2], w[ch].h[2], a);
        a = fdot2(hv.h[3], w[ch].h[3], a);
        ac[ch & 3] = a;
      }
    }
    part[kq][c] = (ac[0] + ac[1]) + (ac[2] + ac[3]);
    __syncthreads();

    // ---- gate assembly ----
    if (tid < 256)
      glf[c] = part[0][c] + part[1][c] + (L ? bsv : g1v);
    __syncthreads();

    // ---- elementwise + publish (wave 0) ----
    if (tid < 64) {
      float gi = glf[j], gj = glf[64 + j], gf = glf[128 + j], go = glf[192 + j];
      float cn = cst * sigm(gf + 1.f) + sigm(gi) * tanh_(gj);
      cst = cn;
      float h = tanh_(cn) * sigm(go);
      hlds[j] = (half_t)h;
      if (L) {
        size_t oi = ((size_t)b * 2048 + t) * 256 + s * 64 + j;
        if (fp32) ((float*)dout)[oi] = h;
        else      ((unsigned short*)dout)[oi] = f2bf(h);
      }
    }
    if (tid < 8) {                    // same wave: LDS RAW within wave is ordered
      uint4 hv4 = *(const uint4*)&hlds[tid * 8];
      half_t* dst = L ? (H2r + ((size_t)((t + 1) & 3) * 32 + b) * 256 + s * 64)
                      : (H1 + ((size_t)(t + 1) * 32 + b) * 256 + s * 64);
      *(uint4*)(dst + tid * 8) = hv4;
    }
    if (tid == 0)
      __hip_atomic_store(&fOwn[(t + 1) * 128 + b * 4 + s], 1, __ATOMIC_RELEASE,
                         __HIP_MEMORY_SCOPE_AGENT);
    __syncthreads();                  // glf/part reuse guard for next t
  }
}

// ----------------------------------------------------------------------------
extern "C" void kernel_launch(void* const* d_in, const int* in_sizes, int n_in,
                              void* d_out, int out_size, void* d_ws, size_t ws_size,
                              hipStream_t stream) {
  const void* x  = d_in[0];   // [32][2048][256]
  const void* W0 = d_in[1];   // [512][1024]
  const void* b0 = d_in[2];   // [1024]
  const void* W1 = d_in[3];   // [512][1024]
  const void* b1 = d_in[4];   // [1024]

  char* p = (char*)d_ws;                                   // ~172 MB total
  half_t* G1   = (half_t*)p;  p += (size_t)134217728;      // 65536x1024 f16
  half_t* H1   = (half_t*)p;  p += (size_t)33570816;       // 2049x32x256 f16
  half_t* H2r  = (half_t*)p;  p += 65536;                  // 4x32x256 f16
  half_t* Wrec = (half_t*)p;  p += 1572864;                // 98304 uint4
  half_t* BT0  = (half_t*)p;  p += 524288;                 // 1024x256 f16
  float* bias0 = (float*)p;   p += 4096;
  float* bias1 = (float*)p;   p += 4096;
  int* flag1   = (int*)p;     p += 1049088;                // 2049x32x4 int
  int* flag2   = (int*)p;     p += 1049088;
  int* dflag   = (int*)p;     p += 256;

  detect<<<1, 256, 0, stream>>>((const unsigned short*)x, dflag);
  prep<<<dim3(3072, 5), 256, 0, stream>>>(W0, W1, b0, b1, dflag,
                                          Wrec, BT0, bias0, bias1,
                                          H1, H2r, flag1, flag2);
  gemm_xw<<<dim3(512, 8), 256, 0, stream>>>(x, BT0, bias0, G1, dflag);
  recur<<<256, 512, 0, stream>>>(G1, (const uint4*)Wrec, bias1,
                                 H1, H2r, flag1, flag2, d_out, dflag);
}

// Round 5
// 3189.704 us; speedup vs baseline: 6.7170x; 3.1384x over previous
//
#include <hip/hip_runtime.h>
#include <hip/hip_bf16.h>
#include <hip/hip_fp16.h>

// ============================================================================
// 2-layer LSTM (TF BasicLSTMCell, forget_bias=1), B=32, T=2048, D=H=256.
// R5: fully fused persistent recurrence, no GEMM.
//   256 WGs = 2 layers x 4 column-slices x 32 batches, 512 threads
//   (thread = K-half kq x column c). Weights: 32 NAMED uint4 vars = 128 VGPRs
//   (R3/R4 bug: union/array forms spilled to scratch -> VGPR_Count 84/140).
//   Cross-WG handoff: tagged-word protocol — every f16 published as one
//   relaxed agent-scope 4B atomic (t<<16 | f16bits); consumers poll until
//   tag==t. No fences, no wbl2/inv, poison-safe (0xAAAA tag never matches).
//   H1 = write-once trace [2048][32][256]; H2 = depth-4 ring (skew<=1).
// ============================================================================

typedef _Float16 half_t;
typedef __attribute__((ext_vector_type(2))) _Float16 h2v;

static __device__ __forceinline__ float bf2f(unsigned short u) {
  union { unsigned u; float f; } v; v.u = ((unsigned)u) << 16; return v.f;
}
static __device__ __forceinline__ unsigned short f2bf(float f) {
  union { float f; unsigned u; } v; v.f = f;
  unsigned r = v.u + 0x7fffu + ((v.u >> 16) & 1u);
  return (unsigned short)(r >> 16);
}
static __device__ __forceinline__ float ldw(const void* p, long i, int fp32) {
  return fp32 ? ((const float*)p)[i] : bf2f(((const unsigned short*)p)[i]);
}
static __device__ __forceinline__ unsigned short f16b(float f) {
  return __builtin_bit_cast(unsigned short, (half_t)f);
}
static __device__ __forceinline__ h2v BC(unsigned u) {
  return __builtin_bit_cast(h2v, u);
}
static __device__ __forceinline__ float rcpf(float x) { return __builtin_amdgcn_rcpf(x); }
static __device__ __forceinline__ float sigm(float x) { return rcpf(1.f + __expf(-x)); }
static __device__ __forceinline__ float tanh_(float x) {
  float e = __expf(-2.f * fabsf(x));
  float t = (1.f - e) * rcpf(1.f + e);
  return copysignf(t, x);
}
static __device__ __forceinline__ float fdot2(h2v a, h2v b, float c) {
#if __has_builtin(__builtin_amdgcn_fdot2)
  return __builtin_amdgcn_fdot2(a, b, c, false);
#else
  return c + (float)a.x * (float)b.x + (float)a.y * (float)b.y;
#endif
}

// ---------------------------------------------------------------- detect ----
__global__ __launch_bounds__(256) void detect(const unsigned short* __restrict__ x,
                                              int* __restrict__ flag) {
  __shared__ int cnt;
  if (threadIdx.x == 0) cnt = 0;
  __syncthreads();
  int c = 0;
#pragma unroll
  for (int i = 0; i < 8; ++i) {
    unsigned short u = x[threadIdx.x * 8 + i];
    c += (((u >> 7) & 0xFF) >= 192) ? 1 : 0;
  }
  atomicAdd(&cnt, c);
  __syncthreads();
  if (threadIdx.x == 0) *flag = (cnt > 16) ? 1 : 0;
}

// ------------------------------------------------------------------ prep ----
// task0 (y=0): Wrec packed u32 words. u = (sL*512 + tid)*128 + i, sL=L*4+s.
//   kq=tid>>8, c=tid&255, col=(c>>6)*256 + s*64 + (c&63), rows kq*256+2i,+1
//   from W_L ([512][1024]); word = f16lo | f16hi<<16.
// task1 (y=1): biases -> fp32.
// ----------------------------------------------------------------------------
__global__ __launch_bounds__(256) void prep(
    const void* __restrict__ W0, const void* __restrict__ W1,
    const void* __restrict__ b0, const void* __restrict__ b1,
    const int* __restrict__ dtf,
    unsigned* __restrict__ Wrec, float* __restrict__ bias0,
    float* __restrict__ bias1)
{
  const int fp32 = *dtf;
  int id = blockIdx.x * 256 + threadIdx.x;
  if (blockIdx.y == 0) {
    int i  = id & 127;
    int tid = (id >> 7) & 511;
    int sL = id >> 16;                 // 0..7 = L*4+s
    int L = sL >> 2, s = sL & 3;
    int kq = tid >> 8, c = tid & 255;
    int col = ((c >> 6) << 8) + s * 64 + (c & 63);
    long r0 = (long)(kq * 256 + 2 * i) * 1024 + col;
    const void* W = L ? W1 : W0;
    unsigned lo = f16b(ldw(W, r0, fp32));
    unsigned hi = f16b(ldw(W, r0 + 1024, fp32));
    Wrec[id] = lo | (hi << 16);
  } else {
    if (id < 1024)       bias0[id] = ldw(b0, id, fp32);
    else if (id < 2048)  bias1[id - 1024] = ldw(b1, id - 1024, fp32);
  }
}

// ----------------------------------------------------------------- recur ----
__global__ __launch_bounds__(512) void recur(
    const void* __restrict__ x, const unsigned* __restrict__ Wrec,
    const float* __restrict__ bias0, const float* __restrict__ bias1,
    unsigned* H1T, unsigned* H2R,
    void* __restrict__ dout, const int* __restrict__ dtf)
{
  const int fp32 = *dtf;
  const int bi = blockIdx.x;
  const int L = bi >> 7, sL = bi >> 5, s = sL & 3, b = bi & 31;
  const int tid = threadIdx.x;
  const int kq = tid >> 8, c = tid & 255;
  const int hbase = kq << 5;

  __shared__ __align__(16) unsigned short hbufh[512];
  __shared__ float part[2][256];
  __shared__ float bg[256];

  // ---- weights: 32 named uint4 = 128 VGPRs, loaded once ----
  const uint4* wp4 = (const uint4*)Wrec + ((size_t)sL * 512 + tid) * 32;
  uint4 w00 = wp4[0],  w01 = wp4[1],  w02 = wp4[2],  w03 = wp4[3];
  uint4 w04 = wp4[4],  w05 = wp4[5],  w06 = wp4[6],  w07 = wp4[7];
  uint4 w08 = wp4[8],  w09 = wp4[9],  w10 = wp4[10], w11 = wp4[11];
  uint4 w12 = wp4[12], w13 = wp4[13], w14 = wp4[14], w15 = wp4[15];
  uint4 w16 = wp4[16], w17 = wp4[17], w18 = wp4[18], w19 = wp4[19];
  uint4 w20 = wp4[20], w21 = wp4[21], w22 = wp4[22], w23 = wp4[23];
  uint4 w24 = wp4[24], w25 = wp4[25], w26 = wp4[26], w27 = wp4[27];
  uint4 w28 = wp4[28], w29 = wp4[29], w30 = wp4[30], w31 = wp4[31];

  if (tid < 256) {
    int scol = ((c >> 6) << 8) + s * 64 + (c & 63);
    bg[c] = (L ? bias1 : bias0)[scol];
  }

  const uint4* hbufu4 = (const uint4*)hbufh;
  float cst = 0.f;

  for (int t = 0; t < 2048; ++t) {
    const int t1 = t - 1;
    // ---- stage inputs (tagged-word poll / plain x load) ----
    if (!L) {
      if (tid < 256) {
        size_t xi = ((size_t)b * 2048 + t) * 256 + tid;
        float xv = fp32 ? ((const float*)x)[xi]
                        : bf2f(((const unsigned short*)x)[xi]);
        hbufh[tid] = f16b(xv);
      } else if (t == 0) {
        hbufh[tid] = 0;
      } else {
        const unsigned* pw = H1T + ((size_t)t1 * 32 + b) * 256 + (tid - 256);
        unsigned v;
        do { v = __hip_atomic_load(pw, __ATOMIC_RELAXED,
                                   __HIP_MEMORY_SCOPE_AGENT); }
        while ((v >> 16) != (unsigned)t1);
        hbufh[tid] = (unsigned short)v;
      }
    } else {
      if (tid < 256) {
        const unsigned* pw = H1T + ((size_t)t * 32 + b) * 256 + tid;
        unsigned v;
        do { v = __hip_atomic_load(pw, __ATOMIC_RELAXED,
                                   __HIP_MEMORY_SCOPE_AGENT); }
        while ((v >> 16) != (unsigned)t);
        hbufh[tid] = (unsigned short)v;
      } else if (t == 0) {
        hbufh[tid] = 0;
      } else {
        const unsigned* pw = H2R + ((size_t)(t1 & 3) * 32 + b) * 256 + (tid - 256);
        unsigned v;
        do { v = __hip_atomic_load(pw, __ATOMIC_RELAXED,
                                   __HIP_MEMORY_SCOPE_AGENT); }
        while ((v >> 16) != (unsigned)t1);
        hbufh[tid] = (unsigned short)v;
      }
    }
    __syncthreads();

    // ---- matvec: 32 broadcast LDS uint4 reads + 128 v_dot2_f32_f16 ----
    float a0 = 0.f, a1 = 0.f, a2 = 0.f, a3 = 0.f;
#define STEPW(W_, I_) { uint4 hv = hbufu4[hbase + I_];      \
    a0 = fdot2(BC(hv.x), BC(W_.x), a0);                     \
    a1 = fdot2(BC(hv.y), BC(W_.y), a1);                     \
    a2 = fdot2(BC(hv.z), BC(W_.z), a2);                     \
    a3 = fdot2(BC(hv.w), BC(W_.w), a3); }
    STEPW(w00, 0)  STEPW(w01, 1)  STEPW(w02, 2)  STEPW(w03, 3)
    STEPW(w04, 4)  STEPW(w05, 5)  STEPW(w06, 6)  STEPW(w07, 7)
    STEPW(w08, 8)  STEPW(w09, 9)  STEPW(w10, 10) STEPW(w11, 11)
    STEPW(w12, 12) STEPW(w13, 13) STEPW(w14, 14) STEPW(w15, 15)
    STEPW(w16, 16) STEPW(w17, 17) STEPW(w18, 18) STEPW(w19, 19)
    STEPW(w20, 20) STEPW(w21, 21) STEPW(w22, 22) STEPW(w23, 23)
    STEPW(w24, 24) STEPW(w25, 25) STEPW(w26, 26) STEPW(w27, 27)
    STEPW(w28, 28) STEPW(w29, 29) STEPW(w30, 30) STEPW(w31, 31)
#undef STEPW
    part[kq][c] = (a0 + a1) + (a2 + a3);
    __syncthreads();

    // ---- elementwise + publish (wave 0); gate order (i, j, f, o) ----
    if (tid < 64) {
      int j = tid;
      float gi = part[0][j]       + part[1][j]       + bg[j];
      float gj = part[0][64 + j]  + part[1][64 + j]  + bg[64 + j];
      float gf = part[0][128 + j] + part[1][128 + j] + bg[128 + j];
      float go = part[0][192 + j] + part[1][192 + j] + bg[192 + j];
      float cn = cst * sigm(gf + 1.f) + sigm(gi) * tanh_(gj);
      cst = cn;
      float h = tanh_(cn) * sigm(go);
      unsigned val = ((unsigned)t << 16) | (unsigned)f16b(h);
      if (!L) {
        __hip_atomic_store(H1T + ((size_t)t * 32 + b) * 256 + s * 64 + j, val,
                           __ATOMIC_RELAXED, __HIP_MEMORY_SCOPE_AGENT);
      } else {
        __hip_atomic_store(H2R + ((size_t)(t & 3) * 32 + b) * 256 + s * 64 + j,
                           val, __ATOMIC_RELAXED, __HIP_MEMORY_SCOPE_AGENT);
        size_t oi = ((size_t)b * 2048 + t) * 256 + s * 64 + j;
        if (fp32) ((float*)dout)[oi] = h;
        else      ((unsigned short*)dout)[oi] = f2bf(h);
      }
    }
    // no barrier here: hbuf rewrite is fenced by the stage barrier (part
    // readers done), part rewrite by next iteration's first barrier.
  }
}

// ----------------------------------------------------------------------------
extern "C" void kernel_launch(void* const* d_in, const int* in_sizes, int n_in,
                              void* d_out, int out_size, void* d_ws, size_t ws_size,
                              hipStream_t stream) {
  const void* x  = d_in[0];   // [32][2048][256]
  const void* W0 = d_in[1];   // [512][1024]
  const void* b0 = d_in[2];   // [1024]
  const void* W1 = d_in[3];   // [512][1024]
  const void* b1 = d_in[4];   // [1024]

  char* p = (char*)d_ws;                                   // ~69.3 MB total
  unsigned* Wrec = (unsigned*)p; p += (size_t)524288 * 4;  // 2 MB packed f16x2
  unsigned* H1T  = (unsigned*)p; p += (size_t)2048 * 32 * 256 * 4;  // 67.1 MB
  unsigned* H2R  = (unsigned*)p; p += (size_t)4 * 32 * 256 * 4;     // 128 KB
  float* bias0   = (float*)p;    p += 4096;
  float* bias1   = (float*)p;    p += 4096;
  int* dflag     = (int*)p;      p += 256;

  detect<<<1, 256, 0, stream>>>((const unsigned short*)x, dflag);
  prep<<<dim3(2048, 2), 256, 0, stream>>>(W0, W1, b0, b1, dflag,
                                          Wrec, bias0, bias1);
  recur<<<256, 512, 0, stream>>>(x, Wrec, bias0, bias1,
                                 H1T, H2R, d_out, dflag);
}